// Round 1
// baseline (376.137 us; speedup 1.0000x reference)
//
#include <hip/hip_runtime.h>
#include <stdint.h>

#define BATCH 4
#define CH 256
#define HSZ 128
#define WSZ 128
#define NPIX (HSZ*WSZ)   // 16384
#define OC 512
#define NHEADS 8

typedef _Float16 f16;
typedef _Float16 f16x4 __attribute__((ext_vector_type(4)));
typedef _Float16 f16x8 __attribute__((ext_vector_type(8)));
typedef float f32x4 __attribute__((ext_vector_type(4)));

__device__ __forceinline__ void async16(const void* g, void* l) {
  __builtin_amdgcn_global_load_lds((const __attribute__((address_space(1))) unsigned int*)g,
                                   (__attribute__((address_space(3))) unsigned int*)l, 16, 0, 0);
}

// ---------- K0: convert both qkv weight matrices to f16 ----------
__global__ void k_prep(const float* __restrict__ wr, const float* __restrict__ wch,
                       f16* __restrict__ w16) {
  int q = blockIdx.x * 256 + threadIdx.x;       // 65536 threads, one float4 each
  float4 v;
  if (q < 32768) v = ((const float4*)wr)[q];
  else           v = ((const float4*)wch)[q - 32768];
  f16x4 h = { (f16)v.x, (f16)v.y, (f16)v.z, (f16)v.w };
  *(f16x4*)(w16 + (size_t)q*4) = h;
}

// ---------- K1: transpose x (B,C,N) f32 -> xT (mod,b,N,C) f16 ----------
__global__ void k_trans(const float* __restrict__ rgb, const float* __restrict__ chm,
                        f16* __restrict__ xT) {
  int bi = blockIdx.x;
  int nt = bi & 255, ct = (bi>>8)&3, b = (bi>>10)&3, mod = bi>>12;
  int n0 = nt*64, c0 = ct*64;
  const float* x = (mod ? chm : rgb) + (size_t)b*CH*NPIX;
  __shared__ __align__(16) f16 t[64][72];
  int tid = threadIdx.x;
#pragma unroll
  for (int rr=0; rr<4; rr++) {
    int chunk = tid + 256*rr;
    int c = chunk >> 4, n4 = (chunk & 15) * 4;
    float4 v = *(const float4*)(x + (size_t)(c0+c)*NPIX + n0 + n4);
    t[n4+0][c] = (f16)v.x; t[n4+1][c] = (f16)v.y;
    t[n4+2][c] = (f16)v.z; t[n4+3][c] = (f16)v.w;
  }
  __syncthreads();
  f16* dst = xT + (size_t)(mod*BATCH + b)*NPIX*CH;
#pragma unroll
  for (int rr=0; rr<2; rr++) {
    int chunk = tid + 256*rr;
    int n = chunk >> 3, c8 = (chunk & 7) * 8;
    float4 v = *(const float4*)&t[n][c8];
    *(float4*)(dst + (size_t)(n0+n)*CH + c0 + c8) = v;
  }
}

// ---------- K2: qkv = W @ x (f16 MFMA, 128x128 tile, BK=64, dbuf, T2 swizzle) ----------
__launch_bounds__(256, 2)
__global__ void k_qkv(const f16* __restrict__ w16, const float* __restrict__ br,
                      const float* __restrict__ bc, const f16* __restrict__ xT,
                      f16* __restrict__ qkv) {
  int bi = blockIdx.x;
  int nt = bi & 127, mt = (bi>>7)&3, b = (bi>>9)&3, mod = bi>>11;
  int o0 = mt*128, n0 = nt*128;
  const char* Wb = (const char*)(w16 + (size_t)mod*OC*CH);
  const char* Xb = (const char*)(xT + (size_t)(mod*BATCH+b)*NPIX*CH);
  f16* outp = qkv + (size_t)(mod*BATCH+b)*OC*NPIX;
  const float* bias = mod ? bc : br;

  __shared__ __align__(16) f16 lds[2][2][8192];   // [buf][A/B][128*64] = 64 KiB
  int tid = threadIdx.x, lane = tid & 63, wid = tid >> 6;

  auto stage = [&](int kt, int buf) {
    int kk0b = kt*128;                       // byte offset of this 64-c chunk in a 512B row
#pragma unroll
    for (int j=0;j<4;j++) {
      int slot = wid*256 + j*64 + lane;      // 1024 16B slots per tile
      int row  = slot >> 3;
      int colb = (slot & 7) << 4;
      int scol = colb ^ ((row & 7) << 4);    // inverse-swizzled SOURCE (rule #21)
      async16(Wb + (size_t)(o0+row)*512 + kk0b + scol, (char*)&lds[buf][0][0] + slot*16);
      async16(Xb + (size_t)(n0+row)*512 + kk0b + scol, (char*)&lds[buf][1][0] + slot*16);
    }
  };

  f32x4 acc[4][4] = {};
  int wr = wid >> 1, wc = wid & 1;
  stage(0,0);
  for (int kt=0; kt<4; kt++) {
    __syncthreads();                          // drains vmcnt -> tile kt ready
    if (kt<3) stage(kt+1, (kt+1)&1);          // prefetch next tile during compute
    const char* AT = (const char*)&lds[kt&1][0][0];
    const char* BT = (const char*)&lds[kt&1][1][0];
#pragma unroll
    for (int ks=0; ks<2; ks++) {
      f16x8 af[4], bf[4];
      int cb = ks*64 + ((lane>>4)<<4);
#pragma unroll
      for (int mi=0; mi<4; mi++) {
        int row = wr*64 + mi*16 + (lane&15);
        af[mi] = *(const f16x8*)(AT + row*128 + (cb ^ ((row&7)<<4)));
      }
#pragma unroll
      for (int ni=0; ni<4; ni++) {
        int row = wc*64 + ni*16 + (lane&15);
        bf[ni] = *(const f16x8*)(BT + row*128 + (cb ^ ((row&7)<<4)));
      }
#pragma unroll
      for (int mi=0; mi<4; mi++)
#pragma unroll
        for (int ni=0; ni<4; ni++)
          acc[mi][ni] = __builtin_amdgcn_mfma_f32_16x16x32_f16(af[mi], bf[ni], acc[mi][ni], 0,0,0);
    }
  }
  // epilogue: + bias, store f16. C/D map: col=lane&15, row=(lane>>4)*4+reg
#pragma unroll
  for (int mi=0; mi<4; mi++) {
    int ob = o0 + wr*64 + mi*16 + ((lane>>4)<<2);
#pragma unroll
    for (int ni=0; ni<4; ni++) {
      int n = n0 + wc*64 + ni*16 + (lane&15);
#pragma unroll
      for (int r=0; r<4; r++) {
        float v = acc[mi][ni][r] + bias[ob+r];
        outp[(size_t)(ob+r)*NPIX + n] = (f16)v;
      }
    }
  }
}

// ---------- K3: logits partials  logit[k,d] = sum_n K[k,n] V[d,n] ----------
__global__ void k_logits(const f16* __restrict__ qkv, float* __restrict__ part) {
  int bi = blockIdx.x;                       // 512 = mod(2) b(4) h(8) chunk(8)
  int chunk = bi&7, h=(bi>>3)&7, b=(bi>>6)&3, mod=bi>>8;
  const f16* base = qkv + ((size_t)(mod*BATCH+b)*OC + h*64)*NPIX;
  int tid = threadIdx.x, lane = tid&63, wid = tid>>6;
  int nb = chunk*2048 + wid*512;
  f32x4 a0 = {}, a1 = {};
  const f16* kb  = base + (size_t)(16 + (lane&15))*NPIX;
  const f16* v0b = base + (size_t)(32 + (lane&15))*NPIX;
  const f16* v1b = base + (size_t)(48 + (lane&15))*NPIX;
  int goff = (lane>>4)<<3;
  for (int it=0; it<16; it++) {
    int n = nb + it*32 + goff;
    f16x8 ka  = *(const f16x8*)(kb  + n);
    f16x8 vb0 = *(const f16x8*)(v0b + n);
    f16x8 vb1 = *(const f16x8*)(v1b + n);
    a0 = __builtin_amdgcn_mfma_f32_16x16x32_f16(ka, vb0, a0, 0,0,0);
    a1 = __builtin_amdgcn_mfma_f32_16x16x32_f16(ka, vb1, a1, 0,0,0);
  }
  __shared__ float red[4][512];
  int d = lane&15, kbase = (lane>>4)<<2;
#pragma unroll
  for (int r=0;r<4;r++) {
    red[wid][(kbase+r)*32 + d]      = a0[r];
    red[wid][(kbase+r)*32 + 16 + d] = a1[r];
  }
  __syncthreads();
#pragma unroll
  for (int rr=0; rr<2; rr++) {
    int e = tid + rr*256;
    part[(size_t)bi*512 + e] = red[0][e]+red[1][e]+red[2][e]+red[3][e];
  }
}

// ---------- K4: reduce partials + softmax over d ----------
__global__ void k_softmax(const float* __restrict__ part, float* __restrict__ attn) {
  int bi = blockIdx.x;       // 64 = mod*4b*8h
  int e = threadIdx.x;       // 512 = 16k * 32d
  float v = 0.f;
#pragma unroll
  for (int c=0;c<8;c++) v += part[((size_t)bi*8 + c)*512 + e];
  float m = v;
  for (int off=16; off; off>>=1) m = fmaxf(m, __shfl_xor(m, off, 32));
  float p = __expf(v - m);
  float s = p;
  for (int off=16; off; off>>=1) s += __shfl_xor(s, off, 32);
  attn[(size_t)bi*512 + e] = p / s;
}

// ---------- K5: depthwise 3x3 on v (both mods) + biases -> writes d_out ----------
__global__ void k_dw(const f16* __restrict__ qkv, const float* __restrict__ wr,
                     const float* __restrict__ brr, const float* __restrict__ wc,
                     const float* __restrict__ bcc, float* __restrict__ out) {
  int bi = blockIdx.x;                       // 8192 = b(4) c(256) yt(8)
  int yt = bi&7, c = (bi>>3)&255, b = bi>>11;
  int tid = threadIdx.x;
  int y = yt*16 + (tid>>4), xg = (tid&15)*8;
  int o = ((c>>5)<<6) + 32 + (c&31);         // v channel within qkv
  float acc[8];
  float bsum = brr[c] + bcc[c];
#pragma unroll
  for (int j=0;j<8;j++) acc[j] = bsum;
#pragma unroll
  for (int mod=0; mod<2; mod++) {
    const f16* vb = qkv + ((size_t)(mod*BATCH+b)*OC + o)*NPIX;
    const float* w = (mod ? wc : wr) + c*9;
    float wv[9];
#pragma unroll
    for (int i=0;i<9;i++) wv[i] = w[i];
#pragma unroll
    for (int dy=-1; dy<=1; dy++) {
      int yy = y+dy;
      if (yy < 0 || yy >= HSZ) continue;
      const f16* rowp = vb + yy*WSZ;
      float v10[10];
#pragma unroll
      for (int i=0;i<10;i++) {
        int x = xg - 1 + i;
        v10[i] = (x>=0 && x<WSZ) ? (float)rowp[x] : 0.f;
      }
#pragma unroll
      for (int j=0;j<8;j++)
        acc[j] += wv[(dy+1)*3+0]*v10[j] + wv[(dy+1)*3+1]*v10[j+1] + wv[(dy+1)*3+2]*v10[j+2];
    }
  }
  float* op = out + ((size_t)b*CH + c)*NPIX + y*WSZ + xg;
  float4 s0 = {acc[0],acc[1],acc[2],acc[3]};
  float4 s1 = {acc[4],acc[5],acc[6],acc[7]};
  *(float4*)op = s0;
  *(float4*)(op+4) = s1;
}

// ---------- K6: out += c_attn^T rq + r_attn^T cq ----------
__global__ void k_att(const f16* __restrict__ qkv, const float* __restrict__ attn,
                      float* __restrict__ out) {
  int bi = blockIdx.x;                       // 2048 = b(4) h(8) nt(64)
  int nt = bi&63, h=(bi>>6)&7, b=bi>>9;
  int tid = threadIdx.x;
  int n = nt*256 + tid;
  __shared__ float ca[512], ra[512];
  const float* cap = attn + (size_t)((1*BATCH+b)*NHEADS + h)*512;   // c_attn (chm)
  const float* rap = attn + (size_t)((0*BATCH+b)*NHEADS + h)*512;   // r_attn (rgb)
  ca[tid] = cap[tid]; ca[tid+256] = cap[tid+256];
  ra[tid] = rap[tid]; ra[tid+256] = rap[tid+256];
  __syncthreads();
  const f16* rq = qkv + ((size_t)(0*BATCH+b)*OC + h*64)*NPIX + n;
  const f16* cq = qkv + ((size_t)(1*BATCH+b)*OC + h*64)*NPIX + n;
  float qr[16], qc[16];
#pragma unroll
  for (int kk=0;kk<16;kk++) {
    qr[kk] = (float)rq[(size_t)kk*NPIX];
    qc[kk] = (float)cq[(size_t)kk*NPIX];
  }
  float acc[32] = {};
#pragma unroll
  for (int kk=0;kk<16;kk++) {
    float fr = qr[kk], fc = qc[kk];
#pragma unroll
    for (int dg=0;dg<8;dg++) {
      f32x4 c4 = *(const f32x4*)&ca[kk*32 + dg*4];
      f32x4 r4 = *(const f32x4*)&ra[kk*32 + dg*4];
      acc[dg*4+0] += c4[0]*fr + r4[0]*fc;
      acc[dg*4+1] += c4[1]*fr + r4[1]*fc;
      acc[dg*4+2] += c4[2]*fr + r4[2]*fc;
      acc[dg*4+3] += c4[3]*fr + r4[3]*fc;
    }
  }
  float* op = out + ((size_t)b*CH + (h<<5))*NPIX + n;
#pragma unroll
  for (int d=0; d<32; d++) op[(size_t)d*NPIX] += acc[d];
}

extern "C" void kernel_launch(void* const* d_in, const int* in_sizes, int n_in,
                              void* d_out, int out_size, void* d_ws, size_t ws_size,
                              hipStream_t stream) {
  const float* rgb   = (const float*)d_in[0];
  const float* chm   = (const float*)d_in[1];
  const float* rqkvw = (const float*)d_in[2];
  const float* rqkvb = (const float*)d_in[3];
  const float* cqkvw = (const float*)d_in[4];
  const float* cqkvb = (const float*)d_in[5];
  const float* rpew  = (const float*)d_in[6];
  const float* rpeb  = (const float*)d_in[7];
  const float* cpew  = (const float*)d_in[8];
  const float* cpeb  = (const float*)d_in[9];
  float* out = (float*)d_out;

  char* ws = (char*)d_ws;
  f16*   w16  = (f16*)(ws);                                   // 512 KiB
  f16*   xT   = (f16*)(ws + (512u<<10));                      // 64 MiB
  f16*   qkv  = (f16*)(ws + (512u<<10) + (64u<<20));          // 128 MiB
  float* part = (float*)(ws + (512u<<10) + (192u<<20));       // 1 MiB
  float* attn = (float*)(ws + (512u<<10) + (193u<<20));       // 128 KiB

  k_prep   <<<256, 256, 0, stream>>>(rqkvw, cqkvw, w16);
  k_trans  <<<8192,256, 0, stream>>>(rgb, chm, xT);
  k_qkv    <<<4096,256, 0, stream>>>(w16, rqkvb, cqkvb, xT, qkv);
  k_logits <<<512, 256, 0, stream>>>(qkv, part);
  k_softmax<<<64,  512, 0, stream>>>(part, attn);
  k_dw     <<<8192,256, 0, stream>>>(qkv, rpew, rpeb, cpew, cpeb, out);
  k_att    <<<2048,256, 0, stream>>>(qkv, attn, out);
}